// Round 4
// baseline (401.704 us; speedup 1.0000x reference)
//
#include <hip/hip_runtime.h>
#include <math.h>

typedef short s16x8 __attribute__((ext_vector_type(8)));
typedef unsigned short u16x8v __attribute__((ext_vector_type(8)));
typedef unsigned short u16x4v __attribute__((ext_vector_type(4)));
typedef float f32x4 __attribute__((ext_vector_type(4)));

#define HH 28
#define WW 28
#define PP 784
#define CC 128
#define GG 64
#define MT 64     // macro-tile tokens
#define AST 136   // bf16 row stride for 128-ch buffers (272B = 17*16B)
#define GSTB 72   // bf16 row stride for 64-ch buffers (144B = 9*16B)

// ws float offsets
#define OFF_FMT0 0
#define OFF_FMT1 100352
#define OFF_FGT0 200704
#define OFF_FGT1 250880
#define OFF_ACCM0 301056
#define OFF_ACCM1 401408
#define OFF_ACCG0 501760
#define OFF_ACCG1 551936
#define OFF_ACCW0 602112
#define OFF_ACCW1 602896
#define ACC_FLOATS 302624   // accm0..accw1 inclusive
#define OFF_CNT   603680    // 4 ints
#define OFF_CNT2  603684    // 4 ints
#define OFF_NJOBS 603688    // 1 int
#define OFF_JOB   603692    // 1568 ints
#define OFF_WB    605260    // bf16 weights region (ushorts)

// bf16 weight sub-offsets (ushort units), layout [set=(si*2+d)][out][in]
#define WIB 0
#define WZB 98304
#define WDB 147456   // (unused after Wid fusion; kept for layout stability)
#define WOB 245760
#define WYB 344064
#define WIDB 393216  // composite Wi@Wdt, [set][out][in], 98304 ushorts

struct KArgs {
  const float* fm[2]; const float* fg[2];
  const float* flow[2]; const float* sx[2]; const float* sy[2];
  const float* Wi; const float* Wz; const float* Wdt; const float* bdt;
  const float* alog; const float* Wo; const float* Wyg;
  float* fmT[2]; float* fgT[2];
  float* accm[2]; float* accg[2]; float* accw[2];
  int* cnt; int* cnt2; int* njobs; int* job;
  unsigned short* wb;
  float* out;
};

__device__ __forceinline__ int span_group(float avg, int& s) {
  if (fabsf(avg - 15.f) < 1.5f) { s = 15; return 0; }
  if (fabsf(avg - 9.f)  < 1.5f) { s = 9;  return 1; }
  if (fabsf(avg - 5.f)  < 1.5f) { s = 5;  return 2; }
  s = 0; return 3;
}

__device__ __forceinline__ float fast_silu(float x) {
  return x * __builtin_amdgcn_rcpf(1.f + __expf(-x));
}

__device__ __forceinline__ unsigned short f2bf(float f) {
  unsigned u = __float_as_uint(f);
  unsigned r = (u + 0x7fffu + ((u >> 16) & 1u)) >> 16;
  return (unsigned short)r;
}
__device__ __forceinline__ float b2f(unsigned short u) {
  return __uint_as_float(((unsigned)u) << 16);
}

#define MFMA(A_, B_, C_) __builtin_amdgcn_mfma_f32_16x16x32_bf16((A_), (B_), (C_), 0, 0, 0)

__global__ void k_zero(float* p, int n) {
  int j = blockIdx.x * 256 + threadIdx.x;
  if (j < n) p[j] = 0.f;
}

__global__ void k_prep(KArgs a) {
  int j = blockIdx.x * 256 + threadIdx.x;     // 301056 exactly
  int side = j / 150528; int r = j - side * 150528;
  int p = r / 192; int ch = r - p * 192;
  if (ch < CC) a.fmT[side][p * CC + ch] = a.fm[side][ch * PP + p];
  else         a.fgT[side][p * GG + (ch - CC)] = a.fg[side][(ch - CC) * PP + p];
}

// transpose + bf16-convert weights to [set][out][in]
__global__ void k_prepw(KArgs a) {
  int j = blockIdx.x * 256 + threadIdx.x;     // 393216 exactly
  unsigned short* wb = a.wb;
  if (j < 98304) {
    int set = j >> 14, r = j & 16383; int o = r >> 7, c = r & 127;
    wb[WIB + j] = f2bf(a.Wi[set * 16384 + c * 128 + o]);
  } else if (j < 147456) {
    int r = j - 98304; int set = r >> 13, rr = r & 8191; int o = rr >> 6, c = rr & 63;
    wb[WZB + r] = f2bf(a.Wz[set * 8192 + c * 128 + o]);
  } else if (j < 245760) {
    // unused region (kept)
  } else if (j < 344064) {
    int r = j - 245760; int set = r >> 14, rr = r & 16383; int o = rr >> 7, c = rr & 127;
    wb[WOB + r] = f2bf(a.Wo[set * 16384 + c * 128 + o]);
  } else {
    int r = j - 344064; int set = r >> 13, rr = r & 8191; int o = rr >> 7, c = rr & 127;
    wb[WYB + r] = f2bf(a.Wyg[set * 8192 + c * 64 + o]);
  }
}

// composite Wid[set][o][i] = sum_m Wi[set][i][m] * Wdt[set][m][o]  (f32, then bf16)
__global__ void k_prepwid(KArgs a) {
  __shared__ float wi_row[128];
  const int set = blockIdx.x, i = blockIdx.y, o = threadIdx.x;
  wi_row[o] = a.Wi[set * 16384 + i * 128 + o];
  __syncthreads();
  float acc = 0.f;
#pragma unroll 4
  for (int m = 0; m < 128; ++m) acc = fmaf(wi_row[m], a.Wdt[set * 16384 + m * 128 + o], acc);
  a.wb[WIDB + set * 16384 + o * 128 + i] = f2bf(acc);
}

__global__ void k_count(KArgs a) {
  int j = blockIdx.x * 256 + threadIdx.x;
  if (j >= 2 * PP) return;
  int side = j / PP, p = j - side * PP;
  float avg = 0.5f * (a.sx[side][p] + a.sy[side][p]);
  int s; int g = span_group(avg, s);
  if (g < 3) atomicAdd(&a.cnt[g], 1);
}

__global__ void k_assign(KArgs a) {
  int j = blockIdx.x * 256 + threadIdx.x;
  if (j >= 2 * PP) return;
  if (j == 0) a.njobs[0] = a.cnt[0] + a.cnt[1] + a.cnt[2];
  int side = j / PP, p = j - side * PP;
  float avg = 0.5f * (a.sx[side][p] + a.sy[side][p]);
  int s; int g = span_group(avg, s);
  if (g < 3) {
    int base = (g > 0 ? a.cnt[0] : 0) + (g > 1 ? a.cnt[1] : 0);
    int slot = base + atomicAdd(&a.cnt2[g], 1);
    a.job[slot] = (side << 10) | p;
  }
}

__global__ void k_fin(KArgs a) {
  int j = blockIdx.x * 256 + threadIdx.x;     // 301056 exactly
  int side = j / 150528; int r = j - side * 150528;
  int p = r / 192; int ch = r - p * 192;
  float inv = 1.f / fmaxf(a.accw[side][p], 1e-6f);
  if (ch < CC) a.out[side * 100352 + ch * PP + p] = a.accm[side][p * CC + ch] * inv;
  else         a.out[200704 + side * 50176 + (ch - CC) * PP + p] = a.accg[side][p * GG + (ch - CC)] * inv;
}

__launch_bounds__(1024, 8)
__global__ void k_main(KArgs a) {
  __shared__ __align__(16) unsigned short mres[MT * AST];   // bf16 m residual
  __shared__ __align__(16) unsigned short gres[MT * GSTB];  // bf16 g residual
  __shared__ __align__(16) unsigned short xny[MT * AST];    // xnorm, then y (aliased)
  __shared__ __align__(16) unsigned short gnm[MT * GSTB];   // g normalized
  __shared__ float2 DPb[4 * CC];
  __shared__ float carry[4 * CC];
  __shared__ float hs[2 * CC];
  __shared__ float na_s[2 * CC];
  __shared__ float bb_s[2 * CC];
  __shared__ float pw_l[228];
  __shared__ int   tap_i[MT * 4];
  __shared__ float tap_w[MT * 4];
  __shared__ int   sc_i[MT];
  __shared__ float sc_w[MT];
  __shared__ float red[16];

  const int tid = threadIdx.x;
  if (blockIdx.x >= a.njobs[0]) return;
  const int job = a.job[blockIdx.x];
  const int side = job >> 10, p = job & 1023;
  const float avg = 0.5f * (a.sx[side][p] + a.sy[side][p]);
  int s; const int si = span_group(avg, s);
  const int hspan = s >> 1, L = s * s;
  const int py = p / WW, px = p - py * WW;
  const float fdx = a.flow[side][p * 4 + 0], fdy = a.flow[side][p * 4 + 1];
  const float cy = fminf(fmaxf((float)py + fdy, 0.f), (float)(HH - 1));
  const float cx = fminf(fmaxf((float)px + fdx, 0.f), (float)(WW - 1));
  const float* fmT = a.fmT[side]; const float* fgT = a.fgT[side];
  float* accm = a.accm[side]; float* accg = a.accg[side]; float* accw = a.accw[side];

  const unsigned short* wb = a.wb;
  const int sg = tid >> 8;                    // subgroup (16 tokens each)
  const int l = tid & 63, lm = l & 15, g = l >> 4;
  const int wv = (tid >> 6) & 3;              // wave within subgroup
  const int o0 = 32 * wv + lm, o1 = o0 + 16, og = 16 * wv + lm;
  const int trow = sg * 16;                   // token base of subgroup

  if (tid < 256) {
    const int d2 = tid >> 7, c2 = tid & 127;
    na_s[tid] = -__expf(a.alog[(si * 2 + d2) * CC + c2]);
    bb_s[tid] = a.bdt[(si * 2 + d2) * CC + c2];
  }
  if (tid < 2 * CC) hs[tid] = 0.f;
  if (tid < L) {
    const int dyi = tid / s - hspan, dxi = tid % s - hspan;
    pw_l[tid] = __expf(-sqrtf((float)(dyi * dyi + dxi * dxi)) / (0.5f * (float)s));
  }
  __syncthreads();
  { float v = (tid < L) ? pw_l[tid] : 0.f;
#pragma unroll
    for (int off = 32; off > 0; off >>= 1) v += __shfl_xor(v, off);
    if ((tid & 63) == 0) red[tid >> 6] = v; }
  __syncthreads();
  { float tot = 0.f;
#pragma unroll
    for (int k = 0; k < 16; ++k) tot += red[k];
    if (tid < L) pw_l[tid] *= (1.f / tot); }
  __syncthreads();

  for (int t0 = 0; t0 < L; t0 += MT) {
    const int tlen = min(MT, L - t0);
    if (tid < tlen) {
      const int t = t0 + tid;
      const int tq = t / s;
      const int dyi = tq - hspan, dxi = (t - tq * s) - hspan;
      const float ys = cy + (float)dyi, xs = cx + (float)dxi;
      const float y0f = floorf(ys), x0f = floorf(xs);
      const float wy = ys - y0f, wx = xs - x0f;
      const int y0 = (int)y0f, x0 = (int)x0f;
#pragma unroll
      for (int k = 0; k < 4; ++k) {
        const int yi = y0 + (k >> 1), xi = x0 + (k & 1);
        const bool v = (yi >= 0) && (yi < HH) && (xi >= 0) && (xi < WW);
        const int yc = min(max(yi, 0), HH - 1), xc = min(max(xi, 0), WW - 1);
        tap_i[tid * 4 + k] = yc * WW + xc;
        const float wgt = ((k >> 1) ? wy : 1.f - wy) * ((k & 1) ? wx : 1.f - wx);
        tap_w[tid * 4 + k] = v ? wgt : 0.f;
      }
      const int ty = py + dyi, tx = px + dxi;
      const bool sv = (ty >= 0) && (ty < HH) && (tx >= 0) && (tx < WW);
      const int sid2 = sv ? ty * WW + tx : 0;
      const float sw = sv ? pw_l[t] : 0.f;
      sc_i[tid] = sid2; sc_w[tid] = sw;
      if (sw != 0.f) atomicAdd(&accw[sid2], sw);
    }
    __syncthreads();
    // bilinear sampling into bf16 token-major residual tiles
    for (int j = tid; j < tlen * 192; j += 1024) {
      const int tt = j / 192, ch = j - tt * 192;
      const int* ti = &tap_i[tt * 4]; const float* tw = &tap_w[tt * 4];
      if (ch < CC) {
        const float v = tw[0] * fmT[ti[0] * CC + ch] + tw[1] * fmT[ti[1] * CC + ch]
                      + tw[2] * fmT[ti[2] * CC + ch] + tw[3] * fmT[ti[3] * CC + ch];
        mres[tt * AST + ch] = f2bf(v);
      } else {
        const int gc = ch - CC;
        const float v = tw[0] * fgT[ti[0] * GG + gc] + tw[1] * fgT[ti[1] * GG + gc]
                      + tw[2] * fgT[ti[2] * GG + gc] + tw[3] * fgT[ti[3] * GG + gc];
        gres[tt * GSTB + gc] = f2bf(v);
      }
    }

    for (int d = 0; d < 2; ++d) {
      const unsigned short* Wib  = wb + WIB  + (si * 2 + d) * 16384;
      const unsigned short* Widb = wb + WIDB + (si * 2 + d) * 16384;
      const unsigned short* Wzb  = wb + WZB  + (si * 2 + d) * 8192;
      const unsigned short* Wob  = wb + WOB  + (si * 2 + d) * 16384;
      const unsigned short* Wyb  = wb + WYB  + (si * 2 + d) * 8192;
      __syncthreads();   // residuals stable (sampling for d=0, Wo-update for d=1)
      // rmsnorm + bf16 normalized copies (thread = (token tr, chan-group c16))
      { const int tr = tid >> 4, c16 = tid & 15;
        u16x8v mraw = *(const u16x8v*)&mres[tr * AST + c16 * 8];
        u16x4v graw = *(const u16x4v*)&gres[tr * GSTB + c16 * 4];
        float mv[8], gv[4];
#pragma unroll
        for (int k = 0; k < 8; ++k) mv[k] = b2f(mraw[k]);
#pragma unroll
        for (int k = 0; k < 4; ++k) gv[k] = b2f(graw[k]);
        float ssm = 0.f, ssg = 0.f;
#pragma unroll
        for (int k = 0; k < 8; ++k) ssm = fmaf(mv[k], mv[k], ssm);
#pragma unroll
        for (int k = 0; k < 4; ++k) ssg = fmaf(gv[k], gv[k], ssg);
#pragma unroll
        for (int off = 8; off > 0; off >>= 1) { ssm += __shfl_xor(ssm, off); ssg += __shfl_xor(ssg, off); }
        const float sm = rsqrtf(ssm * (1.f / CC) + 1e-5f);
        const float sgs = rsqrtf(ssg * (1.f / GG) + 1e-5f);
        u16x8v xv; u16x4v gx;
#pragma unroll
        for (int k = 0; k < 8; ++k) xv[k] = f2bf(mv[k] * sm);
#pragma unroll
        for (int k = 0; k < 4; ++k) gx[k] = f2bf(gv[k] * sgs);
        *(u16x8v*)&xny[tr * AST + c16 * 8] = xv;
        *(u16x4v*)&gnm[tr * GSTB + c16 * 4] = gx;
      }
      __syncthreads();
      // u = x@Wi ; delta_pre = x@Wid (concurrent) ; z = silu(g@Wz)
      f32x4 u0 = {0.f,0.f,0.f,0.f}, u1 = {0.f,0.f,0.f,0.f};
      f32x4 dt0 = {0.f,0.f,0.f,0.f}, dt1 = {0.f,0.f,0.f,0.f};
      f32x4 z0 = {0.f,0.f,0.f,0.f}, z1 = {0.f,0.f,0.f,0.f};
      const int arow = (trow + lm) * AST, grow = (trow + lm) * GSTB;
#pragma unroll
      for (int ss = 0; ss < 4; ++ss) {
        const int c0 = 32 * ss + g * 8;
        s16x8 av = *(const s16x8*)&xny[arow + c0];
        s16x8 b0 = *(const s16x8*)&Wib[o0 * 128 + c0];
        s16x8 b1 = *(const s16x8*)&Wib[o1 * 128 + c0];
        u0 = MFMA(av, b0, u0); u1 = MFMA(av, b1, u1);
        s16x8 e0 = *(const s16x8*)&Widb[o0 * 128 + c0];
        s16x8 e1 = *(const s16x8*)&Widb[o1 * 128 + c0];
        dt0 = MFMA(av, e0, dt0); dt1 = MFMA(av, e1, dt1);
      }
#pragma unroll
      for (int ss = 0; ss < 2; ++ss) {
        const int c0 = 32 * ss + g * 8;
        s16x8 av = *(const s16x8*)&gnm[grow + c0];
        s16x8 b0 = *(const s16x8*)&Wzb[o0 * 64 + c0];
        s16x8 b1 = *(const s16x8*)&Wzb[o1 * 64 + c0];
        z0 = MFMA(av, b0, z0); z1 = MFMA(av, b1, z1);
      }
#pragma unroll
      for (int r = 0; r < 4; ++r) { z0[r] = fast_silu(z0[r]); z1[r] = fast_silu(z1[r]); }
      // decay/x_in + local 4-seg scan (lane holds tokens trow+4g+r of chans o0,o1)
      const float bb0 = bb_s[d * CC + o0], bb1 = bb_s[d * CC + o1];
      const float na0 = na_s[d * CC + o0], na1 = na_s[d * CC + o1];
      float Pl0[4], Dl0[4], Pl1[4], Dl1[4];
      { float P = 0.f, D = 1.f;
#pragma unroll
        for (int r = 0; r < 4; ++r) {
          const float x = dt0[r] + bb0;
          float dlt = fmaxf(x, 0.f) + __logf(1.f + __expf(-fabsf(x)));
          float dec = __expf(dlt * na0), xin = dlt * u0[r];
          if (trow + 4 * g + r >= tlen) { dec = 1.f; xin = 0.f; }
          P = dec * P + xin; D *= dec; Pl0[r] = P; Dl0[r] = D;
        } }
      { float P = 0.f, D = 1.f;
#pragma unroll
        for (int r = 0; r < 4; ++r) {
          const float x = dt1[r] + bb1;
          float dlt = fmaxf(x, 0.f) + __logf(1.f + __expf(-fabsf(x)));
          float dec = __expf(dlt * na1), xin = dlt * u1[r];
          if (trow + 4 * g + r >= tlen) { dec = 1.f; xin = 0.f; }
          P = dec * P + xin; D *= dec; Pl1[r] = P; Dl1[r] = D;
        } }
      float Pi0 = Pl0[3], Di0 = Dl0[3], Pi1 = Pl1[3], Di1 = Dl1[3];
      { float pa = __shfl_up(Pi0, 16), da = __shfl_up(Di0, 16);
        float pb = __shfl_up(Pi1, 16), db = __shfl_up(Di1, 16);
        if (g >= 1) { Pi0 = Di0 * pa + Pi0; Di0 *= da; Pi1 = Di1 * pb + Pi1; Di1 *= db; }
        pa = __shfl_up(Pi0, 32); da = __shfl_up(Di0, 32);
        pb = __shfl_up(Pi1, 32); db = __shfl_up(Di1, 32);
        if (g >= 2) { Pi0 = Di0 * pa + Pi0; Di0 *= da; Pi1 = Di1 * pb + Pi1; Di1 *= db; } }
      float Pe0 = __shfl_up(Pi0, 16), De0 = __shfl_up(Di0, 16);
      float Pe1 = __shfl_up(Pi1, 16), De1 = __shfl_up(Di1, 16);
      if (g == 0) { Pe0 = 0.f; De0 = 1.f; Pe1 = 0.f; De1 = 1.f; }
      if (g == 3) {
        DPb[sg * CC + o0] = make_float2(Di0, Pi0);
        DPb[sg * CC + o1] = make_float2(Di1, Pi1);
      }
      __syncthreads();     // DP ready (also: all A-frag reads of xny complete)
      if (tid < CC) {
        const int c = tid; float h = hs[d * CC + c];
#pragma unroll
        for (int q = 0; q < 4; ++q) {
          carry[q * CC + c] = h;
          const float2 dp = DPb[q * CC + c];
          h = dp.x * h + dp.y;
        }
        hs[d * CC + c] = h;
      }
      __syncthreads();     // carries ready
      { const float cr0 = De0 * carry[sg * CC + o0] + Pe0;
        const float cr1 = De1 * carry[sg * CC + o1] + Pe1;
#pragma unroll
        for (int r = 0; r < 4; ++r) {
          const int rw = trow + 4 * g + r;
          xny[rw * AST + o0] = f2bf((Dl0[r] * cr0 + Pl0[r]) * z0[r]);
          xny[rw * AST + o1] = f2bf((Dl1[r] * cr1 + Pl1[r]) * z1[r]);
        } }
      __syncthreads();     // y visible
      // m += y @ Wo ; g += silu(y @ Wyg)
      f32x4 dm0 = {0.f,0.f,0.f,0.f}, dm1 = {0.f,0.f,0.f,0.f}, dgv = {0.f,0.f,0.f,0.f};
#pragma unroll
      for (int ss = 0; ss < 4; ++ss) {
        const int c0 = 32 * ss + g * 8;
        s16x8 av = *(const s16x8*)&xny[arow + c0];
        s16x8 b0 = *(const s16x8*)&Wob[o0 * 128 + c0];
        s16x8 b1 = *(const s16x8*)&Wob[o1 * 128 + c0];
        s16x8 bg = *(const s16x8*)&Wyb[og * 128 + c0];
        dm0 = MFMA(av, b0, dm0); dm1 = MFMA(av, b1, dm1);
        dgv = MFMA(av, bg, dgv);
      }
#pragma unroll
      for (int r = 0; r < 4; ++r) {
        const int rw = trow + 4 * g + r;
        mres[rw * AST + o0] = f2bf(b2f(mres[rw * AST + o0]) + dm0[r]);
        mres[rw * AST + o1] = f2bf(b2f(mres[rw * AST + o1]) + dm1[r]);
        gres[rw * GSTB + og] = f2bf(b2f(gres[rw * GSTB + og]) + fast_silu(dgv[r]));
      }
    }
    __syncthreads();   // residuals final for scatter

    for (int j = tid; j < tlen * 192; j += 1024) {
      const int tt = j / 192, ch = j - tt * 192;
      const float w = sc_w[tt];
      if (w != 0.f) {
        const int tgt = sc_i[tt];
        if (ch < CC) atomicAdd(&accm[tgt * CC + ch], b2f(mres[tt * AST + ch]) * w);
        else         atomicAdd(&accg[tgt * GG + (ch - CC)], b2f(gres[tt * GSTB + (ch - CC)]) * w);
      }
    }
    __syncthreads();   // scatter done before next macro-tile overwrites tiles
  }
}

extern "C" void kernel_launch(void* const* d_in, const int* in_sizes, int n_in,
                              void* d_out, int out_size, void* d_ws, size_t ws_size,
                              hipStream_t stream) {
  (void)in_sizes; (void)n_in; (void)out_size; (void)ws_size;
  float* ws = (float*)d_ws;
  KArgs a;
  a.fm[0]  = (const float*)d_in[0]; a.fm[1]  = (const float*)d_in[1];
  a.fg[0]  = (const float*)d_in[2]; a.fg[1]  = (const float*)d_in[3];
  a.flow[0] = (const float*)d_in[4]; a.flow[1] = (const float*)d_in[5];
  a.sx[0] = (const float*)d_in[6]; a.sy[0] = (const float*)d_in[7];
  a.sx[1] = (const float*)d_in[8]; a.sy[1] = (const float*)d_in[9];
  a.Wi  = (const float*)d_in[10]; a.Wz   = (const float*)d_in[11];
  a.Wdt = (const float*)d_in[12]; a.bdt  = (const float*)d_in[13];
  a.alog = (const float*)d_in[14]; a.Wo  = (const float*)d_in[15];
  a.Wyg = (const float*)d_in[16];
  a.fmT[0] = ws + OFF_FMT0; a.fmT[1] = ws + OFF_FMT1;
  a.fgT[0] = ws + OFF_FGT0; a.fgT[1] = ws + OFF_FGT1;
  a.accm[0] = ws + OFF_ACCM0; a.accm[1] = ws + OFF_ACCM1;
  a.accg[0] = ws + OFF_ACCG0; a.accg[1] = ws + OFF_ACCG1;
  a.accw[0] = ws + OFF_ACCW0; a.accw[1] = ws + OFF_ACCW1;
  a.cnt  = (int*)(ws + OFF_CNT);
  a.cnt2 = (int*)(ws + OFF_CNT2);
  a.njobs = (int*)(ws + OFF_NJOBS);
  a.job  = (int*)(ws + OFF_JOB);
  a.wb   = (unsigned short*)(ws + OFF_WB);
  a.out = (float*)d_out;

  k_zero<<<1183, 256, 0, stream>>>(ws + OFF_ACCM0, ACC_FLOATS + 12);
  k_prep<<<1176, 256, 0, stream>>>(a);
  k_prepw<<<1536, 256, 0, stream>>>(a);
  k_prepwid<<<dim3(6, 128), 128, 0, stream>>>(a);
  k_count<<<7, 256, 0, stream>>>(a);
  k_assign<<<7, 256, 0, stream>>>(a);
  k_main<<<1568, 1024, 0, stream>>>(a);
  k_fin<<<1176, 256, 0, stream>>>(a);
}

// Round 8
// 301.580 us; speedup vs baseline: 1.3320x; 1.3320x over previous
//
#include <hip/hip_runtime.h>
#include <math.h>

typedef short s16x8 __attribute__((ext_vector_type(8)));
typedef unsigned short u16x8v __attribute__((ext_vector_type(8)));
typedef float f32x4 __attribute__((ext_vector_type(4)));

#define HH 28
#define WW 28
#define PP 784
#define CC 128
#define GG 64
#define MT 32     // macro-tile tokens (2 halves of 16)
#define AST 136   // bf16 row stride for 128-ch buffers (272B = 17*16B)
#define GSTB 72   // bf16 row stride for 64-ch buffers (144B = 9*16B)

// ---- workspace layout: EXACTLY R3's proven map (3.21 MB < R3's 3.40 MB) ----
#define OFF_FMT0 0
#define OFF_FMT1 100352
#define OFF_FGT0 200704
#define OFF_FGT1 250880
#define OFF_ACCM0 301056
#define OFF_ACCM1 401408
#define OFF_ACCG0 501760
#define OFF_ACCG1 551936
#define OFF_ACCW0 602112
#define OFF_ACCW1 602896
#define ACC_FLOATS 302624   // accm0..accw1 inclusive
#define OFF_CNT   603680    // 4 ints
#define OFF_CNT2  603684    // 4 ints
#define OFF_NJOBS 603688    // 1 int
#define OFF_JOB   603692    // 1568 ints
#define OFF_WB    605260    // bf16 weights, 393216 ushorts (196608 floats)

// bf16 weight sub-offsets (ushort units), layout [set=(si*2+d)][out][in]
#define WIB 0        // Wi^T
#define WZB 98304    // Wz^T
#define WDB 147456   // Wid = (Wi@Wdt)^T  (composite; fills old Wdt slot)
#define WOB 245760   // Wo^T
#define WYB 344064   // Wyg^T

struct KArgs {
  const float* fm[2]; const float* fg[2];
  const float* flow[2]; const float* sx[2]; const float* sy[2];
  const float* Wi; const float* Wz; const float* Wdt; const float* bdt;
  const float* alog; const float* Wo; const float* Wyg;
  float* fmT[2]; float* fgT[2];
  float* accm[2]; float* accg[2]; float* accw[2];
  int* cnt; int* cnt2; int* njobs; int* job;
  unsigned short* wb;
  float* out;
};

__device__ __forceinline__ int span_group(float avg, int& s) {
  if (fabsf(avg - 15.f) < 1.5f) { s = 15; return 0; }
  if (fabsf(avg - 9.f)  < 1.5f) { s = 9;  return 1; }
  if (fabsf(avg - 5.f)  < 1.5f) { s = 5;  return 2; }
  s = 0; return 3;
}

__device__ __forceinline__ float fast_silu(float x) {
  return x * __builtin_amdgcn_rcpf(1.f + __expf(-x));
}

__device__ __forceinline__ unsigned short f2bf(float f) {
  unsigned u = __float_as_uint(f);
  unsigned r = (u + 0x7fffu + ((u >> 16) & 1u)) >> 16;
  return (unsigned short)r;
}
__device__ __forceinline__ float b2f(unsigned short u) {
  return __uint_as_float(((unsigned)u) << 16);
}

#define MFMA(A_, B_, C_) __builtin_amdgcn_mfma_f32_16x16x32_bf16((A_), (B_), (C_), 0, 0, 0)

__global__ void k_zero(float* p, int n) {
  int j = blockIdx.x * 256 + threadIdx.x;
  if (j < n) p[j] = 0.f;
}

// transpose features to [pos][ch], f32
__global__ void k_prep(KArgs a) {
  int j = blockIdx.x * 256 + threadIdx.x;     // 301056 exactly
  int side = j / 150528; int r = j - side * 150528;
  int p = r / 192; int ch = r - p * 192;
  if (ch < CC) a.fmT[side][p * CC + ch] = a.fm[side][ch * PP + p];
  else         a.fgT[side][p * GG + (ch - CC)] = a.fg[side][(ch - CC) * PP + p];
}

// transpose + bf16-convert weights to [set][out][in]; WDB slot left for k_prepwid
__global__ void k_prepw(KArgs a) {
  int j = blockIdx.x * 256 + threadIdx.x;     // 393216 exactly
  unsigned short* wb = a.wb;
  if (j < 98304) {
    int set = j >> 14, r = j & 16383; int o = r >> 7, c = r & 127;
    wb[WIB + j] = f2bf(a.Wi[set * 16384 + c * 128 + o]);
  } else if (j < 147456) {
    int r = j - 98304; int set = r >> 13, rr = r & 8191; int o = rr >> 6, c = rr & 63;
    wb[WZB + r] = f2bf(a.Wz[set * 8192 + c * 128 + o]);
  } else if (j < 245760) {
    // WDB region: written by k_prepwid
  } else if (j < 344064) {
    int r = j - 245760; int set = r >> 14, rr = r & 16383; int o = rr >> 7, c = rr & 127;
    wb[WOB + r] = f2bf(a.Wo[set * 16384 + c * 128 + o]);
  } else {
    int r = j - 344064; int set = r >> 13, rr = r & 8191; int o = rr >> 7, c = rr & 127;
    wb[WYB + r] = f2bf(a.Wyg[set * 8192 + c * 64 + o]);
  }
}

// composite Wid[set][o][i] = sum_m Wi[set][i][m] * Wdt[set][m][o]  (f32, then bf16)
__global__ void k_prepwid(KArgs a) {
  __shared__ float wi_row[128];
  const int set = blockIdx.x, i = blockIdx.y, o = threadIdx.x;
  wi_row[o] = a.Wi[set * 16384 + i * 128 + o];
  __syncthreads();
  float acc = 0.f;
#pragma unroll 4
  for (int m = 0; m < 128; ++m) acc = fmaf(wi_row[m], a.Wdt[set * 16384 + m * 128 + o], acc);
  a.wb[WDB + set * 16384 + o * 128 + i] = f2bf(acc);
}

__global__ void k_count(KArgs a) {
  int j = blockIdx.x * 256 + threadIdx.x;
  if (j >= 2 * PP) return;
  int side = j / PP, p = j - side * PP;
  float avg = 0.5f * (a.sx[side][p] + a.sy[side][p]);
  int s; int g = span_group(avg, s);
  if (g < 3) atomicAdd(&a.cnt[g], 1);
}

__global__ void k_assign(KArgs a) {
  int j = blockIdx.x * 256 + threadIdx.x;
  if (j >= 2 * PP) return;
  if (j == 0) a.njobs[0] = a.cnt[0] + a.cnt[1] + a.cnt[2];
  int side = j / PP, p = j - side * PP;
  float avg = 0.5f * (a.sx[side][p] + a.sy[side][p]);
  int s; int g = span_group(avg, s);
  if (g < 3) {
    int base = (g > 0 ? a.cnt[0] : 0) + (g > 1 ? a.cnt[1] : 0);
    int slot = base + atomicAdd(&a.cnt2[g], 1);
    a.job[slot] = (side << 10) | p;
  }
}

__global__ void k_fin(KArgs a) {
  int j = blockIdx.x * 256 + threadIdx.x;     // 301056 exactly
  int side = j / 150528; int r = j - side * 150528;
  int p = r / 192; int ch = r - p * 192;
  float inv = 1.f / fmaxf(a.accw[side][p], 1e-6f);
  if (ch < CC) a.out[side * 100352 + ch * PP + p] = a.accm[side][p * CC + ch] * inv;
  else         a.out[200704 + side * 50176 + (ch - CC) * PP + p] = a.accg[side][p * GG + (ch - CC)] * inv;
}

__launch_bounds__(256, 4)
__global__ void k_main(KArgs a) {
  __shared__ __align__(16) unsigned short mres[MT * AST];   // bf16 m residual
  __shared__ __align__(16) unsigned short gres[MT * GSTB];  // bf16 g residual
  __shared__ __align__(16) unsigned short bufA[MT * AST];   // xnorm_m, then y
  __shared__ __align__(16) unsigned short bufB[MT * GSTB];  // gnorm
  __shared__ float hs[2 * CC];
  __shared__ float na_s[2 * CC];
  __shared__ float bb_s[2 * CC];
  __shared__ float pw_l[228];
  __shared__ int   tap_i[MT * 4];
  __shared__ float tap_w[MT * 4];
  __shared__ int   sc_i[MT];
  __shared__ float sc_w[MT];
  __shared__ float red[4];

  const int tid = threadIdx.x;
  if (blockIdx.x >= a.njobs[0]) return;
  const int job = a.job[blockIdx.x];
  const int side = job >> 10, p = job & 1023;
  const float avg = 0.5f * (a.sx[side][p] + a.sy[side][p]);
  int s; const int si = span_group(avg, s);
  const int hspan = s >> 1, L = s * s;
  const int py = p / WW, px = p - py * WW;
  const float fdx = a.flow[side][p * 4 + 0], fdy = a.flow[side][p * 4 + 1];
  const float cy = fminf(fmaxf((float)py + fdy, 0.f), (float)(HH - 1));
  const float cx = fminf(fmaxf((float)px + fdx, 0.f), (float)(WW - 1));
  const float* fmT = a.fmT[side]; const float* fgT = a.fgT[side];
  float* accm = a.accm[side]; float* accg = a.accg[side]; float* accw = a.accw[side];

  const unsigned short* wb = a.wb;
  const int wv = tid >> 6, l = tid & 63, lm = l & 15, g = l >> 4;
  const int o0 = 32 * wv + lm, o1 = o0 + 16, og = 16 * wv + lm;

  { const int d2 = tid >> 7, c2 = tid & 127;
    na_s[tid] = -__expf(a.alog[(si * 2 + d2) * CC + c2]);
    bb_s[tid] = a.bdt[(si * 2 + d2) * CC + c2];
    hs[tid] = 0.f; }
  if (tid < L) {
    const int dyi = tid / s - hspan, dxi = tid % s - hspan;
    pw_l[tid] = __expf(-sqrtf((float)(dyi * dyi + dxi * dxi)) / (0.5f * (float)s));
  }
  __syncthreads();
  { float v = (tid < L) ? pw_l[tid] : 0.f;
#pragma unroll
    for (int off = 32; off > 0; off >>= 1) v += __shfl_xor(v, off);
    if ((tid & 63) == 0) red[tid >> 6] = v; }
  __syncthreads();
  { const float pinv = 1.f / (red[0] + red[1] + red[2] + red[3]);
    if (tid < L) pw_l[tid] *= pinv; }
  __syncthreads();

  for (int t0 = 0; t0 < L; t0 += MT) {
    const int tlen = min(MT, L - t0);
    if (tid < tlen) {
      const int t = t0 + tid;
      const int tq = t / s;
      const int dyi = tq - hspan, dxi = (t - tq * s) - hspan;
      const float ys = cy + (float)dyi, xs = cx + (float)dxi;
      const float y0f = floorf(ys), x0f = floorf(xs);
      const float wy = ys - y0f, wx = xs - x0f;
      const int y0 = (int)y0f, x0 = (int)x0f;
#pragma unroll
      for (int k = 0; k < 4; ++k) {
        const int yi = y0 + (k >> 1), xi = x0 + (k & 1);
        const bool v = (yi >= 0) && (yi < HH) && (xi >= 0) && (xi < WW);
        const int yc = min(max(yi, 0), HH - 1), xc = min(max(xi, 0), WW - 1);
        tap_i[tid * 4 + k] = yc * WW + xc;
        const float wgt = ((k >> 1) ? wy : 1.f - wy) * ((k & 1) ? wx : 1.f - wx);
        tap_w[tid * 4 + k] = v ? wgt : 0.f;
      }
      const int ty = py + dyi, tx = px + dxi;
      const bool sv = (ty >= 0) && (ty < HH) && (tx >= 0) && (tx < WW);
      const int sid2 = sv ? ty * WW + tx : 0;
      const float sw = sv ? pw_l[t] : 0.f;
      sc_i[tid] = sid2; sc_w[tid] = sw;
      if (sw != 0.f) atomicAdd(&accw[sid2], sw);
    }
    __syncthreads();   // taps visible
    // bilinear sampling into bf16 token-major residual tiles
    for (int j = tid; j < tlen * 192; j += 256) {
      const int tt = j / 192, ch = j - tt * 192;
      const int* ti = &tap_i[tt * 4]; const float* tw = &tap_w[tt * 4];
      if (ch < CC) {
        const float v = tw[0] * fmT[ti[0] * CC + ch] + tw[1] * fmT[ti[1] * CC + ch]
                      + tw[2] * fmT[ti[2] * CC + ch] + tw[3] * fmT[ti[3] * CC + ch];
        mres[tt * AST + ch] = f2bf(v);
      } else {
        const int gc = ch - CC;
        const float v = tw[0] * fgT[ti[0] * GG + gc] + tw[1] * fgT[ti[1] * GG + gc]
                      + tw[2] * fgT[ti[2] * GG + gc] + tw[3] * fgT[ti[3] * GG + gc];
        gres[tt * GSTB + gc] = f2bf(v);
      }
    }

    for (int d = 0; d < 2; ++d) {
      const unsigned short* Wib  = wb + WIB + (si * 2 + d) * 16384;
      const unsigned short* Widb = wb + WDB + (si * 2 + d) * 16384;
      const unsigned short* Wzb  = wb + WZB + (si * 2 + d) * 8192;
      const unsigned short* Wob  = wb + WOB + (si * 2 + d) * 16384;
      const unsigned short* Wyb  = wb + WYB + (si * 2 + d) * 8192;
      __syncthreads();   // residuals stable (sampling for d=0, update for d=1)
      // rmsnorm: thread = (token tr=tid>>3, chan-group c8=tid&7), 8 lanes/token
      { const int tr = tid >> 3, c8 = tid & 7;
        u16x8v m0 = *(const u16x8v*)&mres[tr * AST + c8 * 16];
        u16x8v m1 = *(const u16x8v*)&mres[tr * AST + c8 * 16 + 8];
        u16x8v gv = *(const u16x8v*)&gres[tr * GSTB + c8 * 8];
        float mv[16], gvf[8];
#pragma unroll
        for (int k = 0; k < 8; ++k) { mv[k] = b2f(m0[k]); mv[8 + k] = b2f(m1[k]); gvf[k] = b2f(gv[k]); }
        float ssm = 0.f, ssg = 0.f;
#pragma unroll
        for (int k = 0; k < 16; ++k) ssm = fmaf(mv[k], mv[k], ssm);
#pragma unroll
        for (int k = 0; k < 8; ++k) ssg = fmaf(gvf[k], gvf[k], ssg);
#pragma unroll
        for (int off = 4; off > 0; off >>= 1) { ssm += __shfl_xor(ssm, off); ssg += __shfl_xor(ssg, off); }
        const float sm = rsqrtf(ssm * (1.f / CC) + 1e-5f);
        const float sgs = rsqrtf(ssg * (1.f / GG) + 1e-5f);
        u16x8v xa, xb, gx;
#pragma unroll
        for (int k = 0; k < 8; ++k) { xa[k] = f2bf(mv[k] * sm); xb[k] = f2bf(mv[8 + k] * sm); gx[k] = f2bf(gvf[k] * sgs); }
        *(u16x8v*)&bufA[tr * AST + c8 * 16] = xa;
        *(u16x8v*)&bufA[tr * AST + c8 * 16 + 8] = xb;
        *(u16x8v*)&bufB[tr * GSTB + c8 * 8] = gx;
      }
      __syncthreads();   // xnorm/gnorm visible
      // u = x@Wi ; delta_pre = x@Wid (same A-frags) ; z = silu(g@Wz); 2 halves
      f32x4 u[2][2], dt[2][2], z[2][2];
#pragma unroll
      for (int h = 0; h < 2; ++h)
#pragma unroll
        for (int j2 = 0; j2 < 2; ++j2) { u[h][j2] = (f32x4){0.f,0.f,0.f,0.f}; dt[h][j2] = (f32x4){0.f,0.f,0.f,0.f}; z[h][j2] = (f32x4){0.f,0.f,0.f,0.f}; }
#pragma unroll
      for (int h = 0; h < 2; ++h) {
        const int ar = (h * 16 + lm) * AST, gr = (h * 16 + lm) * GSTB;
#pragma unroll
        for (int ss = 0; ss < 4; ++ss) {
          const int c0 = 32 * ss + g * 8;
          s16x8 av = *(const s16x8*)&bufA[ar + c0];
          u[h][0]  = MFMA(av, *(const s16x8*)&Wib[o0 * 128 + c0], u[h][0]);
          u[h][1]  = MFMA(av, *(const s16x8*)&Wib[o1 * 128 + c0], u[h][1]);
          dt[h][0] = MFMA(av, *(const s16x8*)&Widb[o0 * 128 + c0], dt[h][0]);
          dt[h][1] = MFMA(av, *(const s16x8*)&Widb[o1 * 128 + c0], dt[h][1]);
        }
#pragma unroll
        for (int ss = 0; ss < 2; ++ss) {
          const int c0 = 32 * ss + g * 8;
          s16x8 gv2 = *(const s16x8*)&bufB[gr + c0];
          z[h][0] = MFMA(gv2, *(const s16x8*)&Wzb[o0 * 64 + c0], z[h][0]);
          z[h][1] = MFMA(gv2, *(const s16x8*)&Wzb[o1 * 64 + c0], z[h][1]);
        }
      }
#pragma unroll
      for (int h = 0; h < 2; ++h)
#pragma unroll
        for (int j2 = 0; j2 < 2; ++j2)
#pragma unroll
          for (int r = 0; r < 4; ++r) z[h][j2][r] = fast_silu(z[h][j2][r]);

      // scan: per channel-group, half A then half B; carry chains in-wave
#pragma unroll
      for (int j2 = 0; j2 < 2; ++j2) {
        const int oc = j2 ? o1 : o0;
        const float bb = bb_s[d * CC + oc], na = na_s[d * CC + oc];
        float hcar = hs[d * CC + oc];
#pragma unroll
        for (int h = 0; h < 2; ++h) {
          float Pl[4], Dl[4]; float P = 0.f, D = 1.f;
#pragma unroll
          for (int r = 0; r < 4; ++r) {
            const float x = dt[h][j2][r] + bb;
            float dlt = fmaxf(x, 0.f) + __logf(1.f + __expf(-fabsf(x)));
            float dec = __expf(dlt * na), xin = dlt * u[h][j2][r];
            if (h * 16 + 4 * g + r >= tlen) { dec = 1.f; xin = 0.f; }
            P = dec * P + xin; D *= dec; Pl[r] = P; Dl[r] = D;
          }
          float Pi = P, Di = D;
          { float pa = __shfl_up(Pi, 16), da = __shfl_up(Di, 16);
            if (g >= 1) { Pi = Di * pa + Pi; Di *= da; }
            pa = __shfl_up(Pi, 32); da = __shfl_up(Di, 32);
            if (g >= 2) { Pi = Di * pa + Pi; Di *= da; } }
          float Pe = __shfl_up(Pi, 16), De = __shfl_up(Di, 16);
          if (g == 0) { Pe = 0.f; De = 1.f; }
          const float cr = De * hcar + Pe;
          const float Pf = __shfl(Pi, 48 + lm), Df = __shfl(Di, 48 + lm);
#pragma unroll
          for (int r = 0; r < 4; ++r) z[h][j2][r] = (Dl[r] * cr + Pl[r]) * z[h][j2][r];  // now y
          hcar = Df * hcar + Pf;
        }
        if (g == 0) hs[d * CC + oc] = hcar;
      }
      __syncthreads();   // all A-frag reads of bufA/bufB complete
#pragma unroll
      for (int h = 0; h < 2; ++h)
#pragma unroll
        for (int r = 0; r < 4; ++r) {
          const int rw = h * 16 + 4 * g + r;
          bufA[rw * AST + o0] = f2bf(z[h][0][r]);
          bufA[rw * AST + o1] = f2bf(z[h][1][r]);
        }
      __syncthreads();   // y visible
      // m += y @ Wo ; g += silu(y @ Wyg)
      f32x4 dm[2][2], dgv[2];
#pragma unroll
      for (int h = 0; h < 2; ++h) { dm[h][0] = (f32x4){0.f,0.f,0.f,0.f}; dm[h][1] = (f32x4){0.f,0.f,0.f,0.f}; dgv[h] = (f32x4){0.f,0.f,0.f,0.f}; }
#pragma unroll
      for (int h = 0; h < 2; ++h) {
        const int ar = (h * 16 + lm) * AST;
#pragma unroll
        for (int ss = 0; ss < 4; ++ss) {
          const int c0 = 32 * ss + g * 8;
          s16x8 av = *(const s16x8*)&bufA[ar + c0];
          dm[h][0] = MFMA(av, *(const s16x8*)&Wob[o0 * 128 + c0], dm[h][0]);
          dm[h][1] = MFMA(av, *(const s16x8*)&Wob[o1 * 128 + c0], dm[h][1]);
          dgv[h]   = MFMA(av, *(const s16x8*)&Wyb[og * 128 + c0], dgv[h]);
        }
      }
#pragma unroll
      for (int h = 0; h < 2; ++h)
#pragma unroll
        for (int r = 0; r < 4; ++r) {
          const int rw = h * 16 + 4 * g + r;
          mres[rw * AST + o0] = f2bf(b2f(mres[rw * AST + o0]) + dm[h][0][r]);
          mres[rw * AST + o1] = f2bf(b2f(mres[rw * AST + o1]) + dm[h][1][r]);
          gres[rw * GSTB + og] = f2bf(b2f(gres[rw * GSTB + og]) + fast_silu(dgv[h][r]));
        }
    }
    __syncthreads();   // residuals final for scatter

    for (int j = tid; j < tlen * 192; j += 256) {
      const int tt = j / 192, ch = j - tt * 192;
      const float w = sc_w[tt];
      if (w != 0.f) {
        const int tgt = sc_i[tt];
        if (ch < CC) atomicAdd(&accm[tgt * CC + ch], b2f(mres[tt * AST + ch]) * w);
        else         atomicAdd(&accg[tgt * GG + (ch - CC)], b2f(gres[tt * GSTB + (ch - CC)]) * w);
      }
    }
    __syncthreads();   // scatter done before next macro-tile overwrites tiles
  }
}

extern "C" void kernel_launch(void* const* d_in, const int* in_sizes, int n_in,
                              void* d_out, int out_size, void* d_ws, size_t ws_size,
                              hipStream_t stream) {
  (void)in_sizes; (void)n_in; (void)out_size; (void)ws_size;
  float* ws = (float*)d_ws;
  KArgs a;
  a.fm[0]  = (const float*)d_in[0]; a.fm[1]  = (const float*)d_in[1];
  a.fg[0]  = (const float*)d_in[2]; a.fg[1]  = (const float*)d_in[3];
  a.flow[0] = (const float*)d_in[4]; a.flow[1] = (const float*)d_in[5];
  a.sx[0] = (const float*)d_in[6]; a.sy[0] = (const float*)d_in[7];
  a.sx[1] = (const float*)d_in[8]; a.sy[1] = (const float*)d_in[9];
  a.Wi  = (const float*)d_in[10]; a.Wz   = (const float*)d_in[11];
  a.Wdt = (const float*)d_in[12]; a.bdt  = (const float*)d_in[13];
  a.alog = (const float*)d_in[14]; a.Wo  = (const float*)d_in[15];
  a.Wyg = (const float*)d_in[16];
  a.fmT[0] = ws + OFF_FMT0; a.fmT[1] = ws + OFF_FMT1;
  a.fgT[0] = ws + OFF_FGT0; a.fgT[1] = ws + OFF_FGT1;
  a.accm[0] = ws + OFF_ACCM0; a.accm[1] = ws + OFF_ACCM1;
  a.accg[0] = ws + OFF_ACCG0; a.accg[1] = ws + OFF_ACCG1;
  a.accw[0] = ws + OFF_ACCW0; a.accw[1] = ws + OFF_ACCW1;
  a.cnt  = (int*)(ws + OFF_CNT);
  a.cnt2 = (int*)(ws + OFF_CNT2);
  a.njobs = (int*)(ws + OFF_NJOBS);
  a.job  = (int*)(ws + OFF_JOB);
  a.wb   = (unsigned short*)(ws + OFF_WB);
  a.out = (float*)d_out;

  k_zero<<<1183, 256, 0, stream>>>(ws + OFF_ACCM0, ACC_FLOATS + 12);
  k_prep<<<1176, 256, 0, stream>>>(a);
  k_prepw<<<1536, 256, 0, stream>>>(a);
  k_prepwid<<<dim3(6, 128), 128, 0, stream>>>(a);
  k_count<<<7, 256, 0, stream>>>(a);
  k_assign<<<7, 256, 0, stream>>>(a);
  k_main<<<1568, 256, 0, stream>>>(a);
  k_fin<<<1176, 256, 0, stream>>>(a);
}